// Round 1
// baseline (314.459 us; speedup 1.0000x reference)
//
#include <hip/hip_runtime.h>
#include <hip/hip_bf16.h>
#include <stdint.h>

#define H_DIM 1024
#define QMAX 127.0f
#define CLIP 2.5f

typedef __attribute__((ext_vector_type(4))) float f32x4;
typedef __attribute__((ext_vector_type(8))) short bf16x8;

// ---------------------------------------------------------------------------
// absmax of clip(x, -CLIP, CLIP) over n elements (n % 4 == 0), atomicMax into *out.
// *out must be pre-zeroed. |clip(x)| == min(|x|, CLIP).
// ---------------------------------------------------------------------------
__global__ __launch_bounds__(256) void absmax_clip_kernel(
    const float* __restrict__ x, long n, float* __restrict__ out) {
  float m = 0.f;
  const long stride = (long)gridDim.x * blockDim.x * 4;
  for (long i = ((long)blockIdx.x * blockDim.x + threadIdx.x) * 4; i < n; i += stride) {
    const float4 v = *reinterpret_cast<const float4*>(x + i);
    m = fmaxf(m, fmaxf(fmaxf(fabsf(v.x), fabsf(v.y)), fmaxf(fabsf(v.z), fabsf(v.w))));
  }
  m = fminf(m, CLIP);
#pragma unroll
  for (int off = 32; off > 0; off >>= 1) m = fmaxf(m, __shfl_down(m, off));
  __shared__ float red[4];
  const int lane = threadIdx.x & 63, w = threadIdx.x >> 6;
  if (lane == 0) red[w] = m;
  __syncthreads();
  if (threadIdx.x == 0) {
    const float mm = fmaxf(fmaxf(red[0], red[1]), fmaxf(red[2], red[3]));
    atomicMax(reinterpret_cast<unsigned int*>(out), __float_as_uint(mm));
  }
}

__device__ __forceinline__ unsigned short quant_bf16(float x, float s) {
  // round(clip(x)*s) is an integer in [-127,127] -> exactly representable in
  // bf16; low 16 mantissa bits of the fp32 are zero, so truncation is exact.
  const float q = rintf(fminf(fmaxf(x, -CLIP), CLIP) * s);
  return (unsigned short)(__float_as_uint(q) >> 16);
}

// ---------------------------------------------------------------------------
// Quantize weight [1024 x 1024] fp32 -> bf16 integer values in ws.
// ---------------------------------------------------------------------------
__global__ __launch_bounds__(256) void quant_w_kernel(
    const float* __restrict__ w, unsigned short* __restrict__ wq,
    const float* __restrict__ amax_p) {
  const float s = QMAX / fmaxf(amax_p[0], 1e-8f);
  const int i = (blockIdx.x * blockDim.x + threadIdx.x) * 4;
  const float4 v = *reinterpret_cast<const float4*>(w + i);
  ushort4 q;
  q.x = quant_bf16(v.x, s);
  q.y = quant_bf16(v.y, s);
  q.z = quant_bf16(v.z, s);
  q.w = quant_bf16(v.w, s);
  *reinterpret_cast<ushort4*>(wq + i) = q;
}

// ---------------------------------------------------------------------------
// Fused GEMM: out[m][n] = (sum_k qA[m][k]*qW[n][k]) * inv_s + bias[n] + resid[m][n]
// A (hidden fp32) is quantized on the fly while staging to LDS.
// 128x128 tile, BK=32, 4 waves (2x2), 16x16x32 bf16 MFMA, 4x4 frags/wave.
// LDS rows padded to 40 ushorts (80B) -> 2-way (free) bank aliasing on b128 reads.
// ---------------------------------------------------------------------------
#define BM 128
#define BN 128
#define BK 32

__global__ __launch_bounds__(256, 2) void gemm_kernel(
    const float* __restrict__ A,        // [M][1024] hidden fp32
    const unsigned short* __restrict__ Wq,  // [1024][1024] quantized bf16 bits
    const float* __restrict__ bias,     // [1024]
    const float* __restrict__ resid,    // [M][1024]
    const float* __restrict__ scales,   // {amax_h, amax_w}
    float* __restrict__ out, int M) {
  __shared__ unsigned short As[BM][40];
  __shared__ unsigned short Bs[BN][40];

  const int nbm = M / BM;
  const int bm = blockIdx.x % nbm;
  const int bn = blockIdx.x / nbm;
  const int m0 = bm * BM, n0 = bn * BN;
  const int t = threadIdx.x;
  const int lane = t & 63, wid = t >> 6;
  const int wr = wid >> 1, wc = wid & 1;  // 2x2 wave grid, 64x64 each
  const int lrow = lane & 15, lgrp = lane >> 4;

  const float amax_h = fmaxf(scales[0], 1e-8f);
  const float amax_w = fmaxf(scales[1], 1e-8f);
  const float sh = QMAX / amax_h;
  const float inv_s = (amax_h * amax_w) / (QMAX * QMAX);

  f32x4 acc[4][4];
#pragma unroll
  for (int i = 0; i < 4; i++)
#pragma unroll
    for (int j = 0; j < 4; j++)
#pragma unroll
      for (int r = 0; r < 4; r++) acc[i][j][r] = 0.f;

  for (int k0 = 0; k0 < H_DIM; k0 += BK) {
    // ---- stage A (fp32 -> quantized bf16 ints), 128x32 tile ----
#pragma unroll
    for (int j = 0; j < 4; ++j) {
      const int f = j * 256 + t;      // 1024 float4 chunks
      const int r = f >> 3, c4 = f & 7;
      const float4 v = *reinterpret_cast<const float4*>(
          A + (size_t)(m0 + r) * H_DIM + k0 + c4 * 4);
      ushort4 q;
      q.x = quant_bf16(v.x, sh);
      q.y = quant_bf16(v.y, sh);
      q.z = quant_bf16(v.z, sh);
      q.w = quant_bf16(v.w, sh);
      *reinterpret_cast<ushort4*>(&As[r][c4 * 4]) = q;
    }
    // ---- stage B (already bf16), 128x32 tile ----
#pragma unroll
    for (int j = 0; j < 2; ++j) {
      const int f = j * 256 + t;      // 512 16B chunks
      const int r = f >> 2, cb = f & 3;
      const uint4 v = *reinterpret_cast<const uint4*>(
          Wq + (size_t)(n0 + r) * H_DIM + k0 + cb * 8);
      *reinterpret_cast<uint4*>(&Bs[r][cb * 8]) = v;
    }
    __syncthreads();

    bf16x8 af[4], bfr[4];
#pragma unroll
    for (int i = 0; i < 4; i++)
      af[i] = *reinterpret_cast<const bf16x8*>(&As[wr * 64 + i * 16 + lrow][lgrp * 8]);
#pragma unroll
    for (int j = 0; j < 4; j++)
      bfr[j] = *reinterpret_cast<const bf16x8*>(&Bs[wc * 64 + j * 16 + lrow][lgrp * 8]);
#pragma unroll
    for (int i = 0; i < 4; i++)
#pragma unroll
      for (int j = 0; j < 4; j++)
        acc[i][j] = __builtin_amdgcn_mfma_f32_16x16x32_bf16(af[i], bfr[j], acc[i][j], 0, 0, 0);
    __syncthreads();
  }

  // ---- epilogue: dequant + bias + residual -> out (pre-LN y) ----
#pragma unroll
  for (int j = 0; j < 4; j++) {
    const int col = n0 + wc * 64 + j * 16 + lrow;
    const float bv = bias[col];
#pragma unroll
    for (int i = 0; i < 4; i++) {
      const int row0 = m0 + wr * 64 + i * 16 + lgrp * 4;
#pragma unroll
      for (int r = 0; r < 4; r++) {
        const size_t off = (size_t)(row0 + r) * H_DIM + col;
        out[off] = acc[i][j][r] * inv_s + bv + resid[off];
      }
    }
  }
}

// ---------------------------------------------------------------------------
// In-place LayerNorm over last dim (1024). One block (256 thr) per row.
// ---------------------------------------------------------------------------
__global__ __launch_bounds__(256) void ln_kernel(
    float* __restrict__ y, const float* __restrict__ gamma,
    const float* __restrict__ beta) {
  const size_t base = (size_t)blockIdx.x * H_DIM + threadIdx.x * 4;
  const float4 v = *reinterpret_cast<const float4*>(y + base);
  float s = v.x + v.y + v.z + v.w;
  float ss = v.x * v.x + v.y * v.y + v.z * v.z + v.w * v.w;
#pragma unroll
  for (int off = 32; off > 0; off >>= 1) {
    s += __shfl_down(s, off);
    ss += __shfl_down(ss, off);
  }
  __shared__ float red[8];
  const int lane = threadIdx.x & 63, w = threadIdx.x >> 6;
  if (lane == 0) { red[w] = s; red[4 + w] = ss; }
  __syncthreads();
  const float stot = red[0] + red[1] + red[2] + red[3];
  const float sstot = red[4] + red[5] + red[6] + red[7];
  const float mu = stot * (1.0f / H_DIM);
  const float var = fmaxf(sstot * (1.0f / H_DIM) - mu * mu, 0.f);
  const float rs = rsqrtf(var + 1e-12f);
  const float4 g = *reinterpret_cast<const float4*>(gamma + threadIdx.x * 4);
  const float4 b = *reinterpret_cast<const float4*>(beta + threadIdx.x * 4);
  float4 o;
  o.x = (v.x - mu) * rs * g.x + b.x;
  o.y = (v.y - mu) * rs * g.y + b.y;
  o.z = (v.z - mu) * rs * g.z + b.z;
  o.w = (v.w - mu) * rs * g.w + b.w;
  *reinterpret_cast<float4*>(y + base) = o;
}

extern "C" void kernel_launch(void* const* d_in, const int* in_sizes, int n_in,
                              void* d_out, int out_size, void* d_ws, size_t ws_size,
                              hipStream_t stream) {
  const float* hidden = (const float*)d_in[0];
  const float* resid  = (const float*)d_in[1];
  const float* weight = (const float*)d_in[2];
  const float* bias   = (const float*)d_in[3];
  const float* gamma  = (const float*)d_in[4];
  const float* beta   = (const float*)d_in[5];
  float* out = (float*)d_out;

  const long nh = (long)in_sizes[0];       // B*S*H
  const int M = (int)(nh / H_DIM);         // 32768 rows

  float* scales = (float*)d_ws;                              // [0]=amax_h, [1]=amax_w
  unsigned short* Wq = (unsigned short*)((char*)d_ws + 64);  // 1024*1024 bf16

  hipMemsetAsync(d_ws, 0, 8, stream);
  absmax_clip_kernel<<<2048, 256, 0, stream>>>(hidden, nh, scales + 0);
  absmax_clip_kernel<<<256, 256, 0, stream>>>(weight, (long)H_DIM * H_DIM, scales + 1);
  quant_w_kernel<<<(H_DIM * H_DIM) / (256 * 4), 256, 0, stream>>>(weight, Wq, scales + 1);
  gemm_kernel<<<(M / BM) * (H_DIM / BN), 256, 0, stream>>>(hidden, Wq, bias, resid, scales, out, M);
  ln_kernel<<<M, 256, 0, stream>>>(out, gamma, beta);
}

// Round 2
// 288.802 us; speedup vs baseline: 1.0888x; 1.0888x over previous
//
#include <hip/hip_runtime.h>
#include <hip/hip_bf16.h>
#include <stdint.h>

#define H_DIM 1024
#define QMAX 127.0f
#define CLIP 2.5f

typedef __attribute__((ext_vector_type(4))) float f32x4;
typedef __attribute__((ext_vector_type(8))) short bf16x8;
typedef __attribute__((address_space(3))) void lds_void;
typedef const __attribute__((address_space(1))) void gmem_void;

// ---------------------------------------------------------------------------
// absmax of clip(x, -CLIP, CLIP) over n elements (n % 4 == 0), atomicMax into *out.
// ---------------------------------------------------------------------------
__global__ __launch_bounds__(256) void absmax_clip_kernel(
    const float* __restrict__ x, long n, float* __restrict__ out) {
  float m = 0.f;
  const long stride = (long)gridDim.x * blockDim.x * 4;
  for (long i = ((long)blockIdx.x * blockDim.x + threadIdx.x) * 4; i < n; i += stride) {
    const float4 v = *reinterpret_cast<const float4*>(x + i);
    m = fmaxf(m, fmaxf(fmaxf(fabsf(v.x), fabsf(v.y)), fmaxf(fabsf(v.z), fabsf(v.w))));
  }
  m = fminf(m, CLIP);
#pragma unroll
  for (int off = 32; off > 0; off >>= 1) m = fmaxf(m, __shfl_down(m, off));
  __shared__ float red[4];
  const int lane = threadIdx.x & 63, w = threadIdx.x >> 6;
  if (lane == 0) red[w] = m;
  __syncthreads();
  if (threadIdx.x == 0) {
    const float mm = fmaxf(fmaxf(red[0], red[1]), fmaxf(red[2], red[3]));
    atomicMax(reinterpret_cast<unsigned int*>(out), __float_as_uint(mm));
  }
}

__device__ __forceinline__ unsigned short quant_bf16(float x, float s) {
  // round(clip(x)*s) is an integer in [-127,127] -> exact in bf16 (low 16
  // mantissa bits of the fp32 are zero, truncation exact).
  const float q = rintf(fminf(fmaxf(x, -CLIP), CLIP) * s);
  return (unsigned short)(__float_as_uint(q) >> 16);
}

// ---------------------------------------------------------------------------
// Quantize fp32 -> bf16 integer values (grid-stride, n % 4 == 0).
// ---------------------------------------------------------------------------
__global__ __launch_bounds__(256) void quant_kernel(
    const float* __restrict__ x, unsigned short* __restrict__ q,
    const float* __restrict__ amax_p, long n) {
  const float s = QMAX / fmaxf(amax_p[0], 1e-8f);
  const long stride = (long)gridDim.x * blockDim.x * 4;
  for (long i = ((long)blockIdx.x * blockDim.x + threadIdx.x) * 4; i < n; i += stride) {
    const float4 v = *reinterpret_cast<const float4*>(x + i);
    ushort4 o;
    o.x = quant_bf16(v.x, s);
    o.y = quant_bf16(v.y, s);
    o.z = quant_bf16(v.z, s);
    o.w = quant_bf16(v.w, s);
    *reinterpret_cast<ushort4*>(q + i) = o;
  }
}

// ---------------------------------------------------------------------------
// m97-structure GEMM on pre-quantized bf16 operands.
// out[m][n] = (sum_k Aq[m][k]*Wq[n][k]) * inv_s + bias[n] + resid[m][n]
// 128x128 tile, BK=32, 4 waves (2x2), 16x16x32 bf16 MFMA, 4x4 frags/wave.
// LDS linear (global_load_lds width=16 direct staging), single-buffered.
// ---------------------------------------------------------------------------
#define BM 128
#define BN 128
#define BK 32

__global__ __launch_bounds__(256, 4) void gemm_q_kernel(
    const unsigned short* __restrict__ Aq,   // [M][1024] bf16 ints
    const unsigned short* __restrict__ Wq,   // [1024][1024] bf16 ints
    const float* __restrict__ bias,
    const float* __restrict__ resid,
    const float* __restrict__ scales,
    float* __restrict__ out, int M) {
  __shared__ __attribute__((aligned(16))) unsigned short As[BM * BK];
  __shared__ __attribute__((aligned(16))) unsigned short Bs[BN * BK];

  const int nwg = (M / BM) * (H_DIM / BN);
  // bijective XCD swizzle (nwg % 8 == 0): each XCD gets a contiguous wg range
  const int cpx = nwg >> 3;
  const int orig = blockIdx.x;
  const int wg = (orig & 7) * cpx + (orig >> 3);
  const int bn = wg & 7;    // H_DIM/BN == 8, fast dim -> A panel reused in L2
  const int bm = wg >> 3;

  const int m0 = bm * BM, n0 = bn * BN;
  const int t = threadIdx.x;
  const int lane = t & 63, wid = t >> 6;
  const int wr = wid >> 1, wc = wid & 1;
  const int lrow = lane & 15, lgrp = lane >> 4;

  const float amax_h = fmaxf(scales[0], 1e-8f);
  const float amax_w = fmaxf(scales[1], 1e-8f);
  const float inv_s = (amax_h * amax_w) / (QMAX * QMAX);

  // staging chunks: 16B chunk c covers row c>>2, ushort col (c&3)*8
  const int c0 = t, c1 = t + 256;
  const int ar0 = c0 >> 2, ac0 = (c0 & 3) * 8;
  const int ar1 = c1 >> 2, ac1 = (c1 & 3) * 8;
  const unsigned short* Ab = Aq + (size_t)m0 * H_DIM;
  const unsigned short* Bb = Wq + (size_t)n0 * H_DIM;

  f32x4 acc[4][4];
#pragma unroll
  for (int i = 0; i < 4; i++)
#pragma unroll
    for (int j = 0; j < 4; j++)
#pragma unroll
      for (int r = 0; r < 4; r++) acc[i][j][r] = 0.f;

  for (int k0 = 0; k0 < H_DIM; k0 += BK) {
    __builtin_amdgcn_global_load_lds(
        (gmem_void*)(Ab + (size_t)ar0 * H_DIM + k0 + ac0), (lds_void*)(As + c0 * 8), 16, 0, 0);
    __builtin_amdgcn_global_load_lds(
        (gmem_void*)(Ab + (size_t)ar1 * H_DIM + k0 + ac1), (lds_void*)(As + c1 * 8), 16, 0, 0);
    __builtin_amdgcn_global_load_lds(
        (gmem_void*)(Bb + (size_t)ar0 * H_DIM + k0 + ac0), (lds_void*)(Bs + c0 * 8), 16, 0, 0);
    __builtin_amdgcn_global_load_lds(
        (gmem_void*)(Bb + (size_t)ar1 * H_DIM + k0 + ac1), (lds_void*)(Bs + c1 * 8), 16, 0, 0);
    __syncthreads();  // drains vmcnt -> LDS tile ready

    bf16x8 af[4], bfr[4];
#pragma unroll
    for (int i = 0; i < 4; i++)
      af[i] = *reinterpret_cast<const bf16x8*>(As + (wr * 64 + i * 16 + lrow) * BK + lgrp * 8);
#pragma unroll
    for (int j = 0; j < 4; j++)
      bfr[j] = *reinterpret_cast<const bf16x8*>(Bs + (wc * 64 + j * 16 + lrow) * BK + lgrp * 8);
#pragma unroll
    for (int i = 0; i < 4; i++)
#pragma unroll
      for (int j = 0; j < 4; j++)
        acc[i][j] = __builtin_amdgcn_mfma_f32_16x16x32_bf16(af[i], bfr[j], acc[i][j], 0, 0, 0);
    __syncthreads();
  }

#pragma unroll
  for (int j = 0; j < 4; j++) {
    const int col = n0 + wc * 64 + j * 16 + lrow;
    const float bv = bias[col];
#pragma unroll
    for (int i = 0; i < 4; i++) {
      const int row0 = m0 + wr * 64 + i * 16 + lgrp * 4;
#pragma unroll
      for (int r = 0; r < 4; r++) {
        const size_t off = (size_t)(row0 + r) * H_DIM + col;
        out[off] = acc[i][j][r] * inv_s + bv + resid[off];
      }
    }
  }
}

// ---------------------------------------------------------------------------
// Fallback fused GEMM (round-1 validated): A quantized on the fly from fp32.
// ---------------------------------------------------------------------------
__global__ __launch_bounds__(256, 2) void gemm_fused_kernel(
    const float* __restrict__ A, const unsigned short* __restrict__ Wq,
    const float* __restrict__ bias, const float* __restrict__ resid,
    const float* __restrict__ scales, float* __restrict__ out, int M) {
  __shared__ unsigned short As[BM][40];
  __shared__ unsigned short Bs[BN][40];
  const int nbm = M / BM;
  const int bm = blockIdx.x % nbm, bn = blockIdx.x / nbm;
  const int m0 = bm * BM, n0 = bn * BN;
  const int t = threadIdx.x;
  const int lane = t & 63, wid = t >> 6;
  const int wr = wid >> 1, wc = wid & 1;
  const int lrow = lane & 15, lgrp = lane >> 4;
  const float amax_h = fmaxf(scales[0], 1e-8f);
  const float amax_w = fmaxf(scales[1], 1e-8f);
  const float sh = QMAX / amax_h;
  const float inv_s = (amax_h * amax_w) / (QMAX * QMAX);
  f32x4 acc[4][4];
#pragma unroll
  for (int i = 0; i < 4; i++)
#pragma unroll
    for (int j = 0; j < 4; j++)
#pragma unroll
      for (int r = 0; r < 4; r++) acc[i][j][r] = 0.f;
  for (int k0 = 0; k0 < H_DIM; k0 += BK) {
#pragma unroll
    for (int j = 0; j < 4; ++j) {
      const int f = j * 256 + t;
      const int r = f >> 3, c4 = f & 7;
      const float4 v = *reinterpret_cast<const float4*>(A + (size_t)(m0 + r) * H_DIM + k0 + c4 * 4);
      ushort4 q;
      q.x = quant_bf16(v.x, sh); q.y = quant_bf16(v.y, sh);
      q.z = quant_bf16(v.z, sh); q.w = quant_bf16(v.w, sh);
      *reinterpret_cast<ushort4*>(&As[r][c4 * 4]) = q;
    }
#pragma unroll
    for (int j = 0; j < 2; ++j) {
      const int f = j * 256 + t;
      const int r = f >> 2, cb = f & 3;
      const uint4 v = *reinterpret_cast<const uint4*>(Wq + (size_t)(n0 + r) * H_DIM + k0 + cb * 8);
      *reinterpret_cast<uint4*>(&Bs[r][cb * 8]) = v;
    }
    __syncthreads();
    bf16x8 af[4], bfr[4];
#pragma unroll
    for (int i = 0; i < 4; i++)
      af[i] = *reinterpret_cast<const bf16x8*>(&As[wr * 64 + i * 16 + lrow][lgrp * 8]);
#pragma unroll
    for (int j = 0; j < 4; j++)
      bfr[j] = *reinterpret_cast<const bf16x8*>(&Bs[wc * 64 + j * 16 + lrow][lgrp * 8]);
#pragma unroll
    for (int i = 0; i < 4; i++)
#pragma unroll
      for (int j = 0; j < 4; j++)
        acc[i][j] = __builtin_amdgcn_mfma_f32_16x16x32_bf16(af[i], bfr[j], acc[i][j], 0, 0, 0);
    __syncthreads();
  }
#pragma unroll
  for (int j = 0; j < 4; j++) {
    const int col = n0 + wc * 64 + j * 16 + lrow;
    const float bv = bias[col];
#pragma unroll
    for (int i = 0; i < 4; i++) {
      const int row0 = m0 + wr * 64 + i * 16 + lgrp * 4;
#pragma unroll
      for (int r = 0; r < 4; r++) {
        const size_t off = (size_t)(row0 + r) * H_DIM + col;
        out[off] = acc[i][j][r] * inv_s + bv + resid[off];
      }
    }
  }
}

// ---------------------------------------------------------------------------
// In-place LayerNorm over last dim (1024). One block (256 thr) per row.
// ---------------------------------------------------------------------------
__global__ __launch_bounds__(256) void ln_kernel(
    float* __restrict__ y, const float* __restrict__ gamma,
    const float* __restrict__ beta) {
  const size_t base = (size_t)blockIdx.x * H_DIM + threadIdx.x * 4;
  const float4 v = *reinterpret_cast<const float4*>(y + base);
  float s = v.x + v.y + v.z + v.w;
  float ss = v.x * v.x + v.y * v.y + v.z * v.z + v.w * v.w;
#pragma unroll
  for (int off = 32; off > 0; off >>= 1) {
    s += __shfl_down(s, off);
    ss += __shfl_down(ss, off);
  }
  __shared__ float red[8];
  const int lane = threadIdx.x & 63, w = threadIdx.x >> 6;
  if (lane == 0) { red[w] = s; red[4 + w] = ss; }
  __syncthreads();
  const float stot = red[0] + red[1] + red[2] + red[3];
  const float sstot = red[4] + red[5] + red[6] + red[7];
  const float mu = stot * (1.0f / H_DIM);
  const float var = fmaxf(sstot * (1.0f / H_DIM) - mu * mu, 0.f);
  const float rs = rsqrtf(var + 1e-12f);
  const float4 g = *reinterpret_cast<const float4*>(gamma + threadIdx.x * 4);
  const float4 b = *reinterpret_cast<const float4*>(beta + threadIdx.x * 4);
  float4 o;
  o.x = (v.x - mu) * rs * g.x + b.x;
  o.y = (v.y - mu) * rs * g.y + b.y;
  o.z = (v.z - mu) * rs * g.z + b.z;
  o.w = (v.w - mu) * rs * g.w + b.w;
  *reinterpret_cast<float4*>(y + base) = o;
}

extern "C" void kernel_launch(void* const* d_in, const int* in_sizes, int n_in,
                              void* d_out, int out_size, void* d_ws, size_t ws_size,
                              hipStream_t stream) {
  const float* hidden = (const float*)d_in[0];
  const float* resid  = (const float*)d_in[1];
  const float* weight = (const float*)d_in[2];
  const float* bias   = (const float*)d_in[3];
  const float* gamma  = (const float*)d_in[4];
  const float* beta   = (const float*)d_in[5];
  float* out = (float*)d_out;

  const long nh = (long)in_sizes[0];   // B*S*H
  const int M = (int)(nh / H_DIM);     // 32768

  float* scales = (float*)d_ws;                               // [0]=amax_h,[1]=amax_w
  unsigned short* Wq = (unsigned short*)((char*)d_ws + 256);  // 2 MB
  unsigned short* Aq = Wq + (size_t)H_DIM * H_DIM;            // 64 MB
  const size_t need = 256 + (size_t)H_DIM * H_DIM * 2 + (size_t)nh * 2;

  hipMemsetAsync(d_ws, 0, 8, stream);
  absmax_clip_kernel<<<2048, 256, 0, stream>>>(hidden, nh, scales + 0);
  absmax_clip_kernel<<<256, 256, 0, stream>>>(weight, (long)H_DIM * H_DIM, scales + 1);
  quant_kernel<<<1024, 256, 0, stream>>>(weight, Wq, scales + 1, (long)H_DIM * H_DIM);

  if (ws_size >= need && (M % BM) == 0) {
    quant_kernel<<<2048, 256, 0, stream>>>(hidden, Aq, scales + 0, nh);
    gemm_q_kernel<<<(M / BM) * (H_DIM / BN), 256, 0, stream>>>(
        Aq, Wq, bias, resid, scales, out, M);
  } else {
    gemm_fused_kernel<<<(M / BM) * (H_DIM / BN), 256, 0, stream>>>(
        hidden, Wq, bias, resid, scales, out, M);
  }
  ln_kernel<<<M, 256, 0, stream>>>(out, gamma, beta);
}

// Round 3
// 255.541 us; speedup vs baseline: 1.2306x; 1.1302x over previous
//
#include <hip/hip_runtime.h>
#include <hip/hip_bf16.h>
#include <stdint.h>

#define H_DIM 1024
#define QMAX 127.0f
#define CLIP 2.5f

typedef __attribute__((ext_vector_type(4))) float f32x4;
typedef __attribute__((ext_vector_type(8))) short bf16x8;
typedef __attribute__((address_space(3))) void lds_void;
typedef const __attribute__((address_space(1))) void gmem_void;

// ---------------------------------------------------------------------------
// absmax of clip(x,-CLIP,CLIP) (n%4==0), atomicMax into *out (pre-zeroed).
// ---------------------------------------------------------------------------
__global__ __launch_bounds__(256) void absmax_clip_kernel(
    const float* __restrict__ x, long n, float* __restrict__ out) {
  float m = 0.f;
  const long stride = (long)gridDim.x * blockDim.x * 4;
  for (long i = ((long)blockIdx.x * blockDim.x + threadIdx.x) * 4; i < n; i += stride) {
    const float4 v = *reinterpret_cast<const float4*>(x + i);
    m = fmaxf(m, fmaxf(fmaxf(fabsf(v.x), fabsf(v.y)), fmaxf(fabsf(v.z), fabsf(v.w))));
  }
  m = fminf(m, CLIP);
#pragma unroll
  for (int off = 32; off > 0; off >>= 1) m = fmaxf(m, __shfl_down(m, off));
  __shared__ float red[4];
  const int lane = threadIdx.x & 63, w = threadIdx.x >> 6;
  if (lane == 0) red[w] = m;
  __syncthreads();
  if (threadIdx.x == 0) {
    const float mm = fmaxf(fmaxf(red[0], red[1]), fmaxf(red[2], red[3]));
    atomicMax(reinterpret_cast<unsigned int*>(out), __float_as_uint(mm));
  }
}

__device__ __forceinline__ unsigned short quant_bf16(float x, float s) {
  // round(clip(x)*s) is an integer in [-127,127] -> exact in bf16.
  const float q = rintf(fminf(fmaxf(x, -CLIP), CLIP) * s);
  return (unsigned short)(__float_as_uint(q) >> 16);
}

// ---------------------------------------------------------------------------
// Quantize fp32 -> bf16 integer values (grid-stride, n%4==0).
// ---------------------------------------------------------------------------
__global__ __launch_bounds__(256) void quant_kernel(
    const float* __restrict__ x, unsigned short* __restrict__ q,
    const float* __restrict__ amax_p, long n) {
  const float s = QMAX / fmaxf(amax_p[0], 1e-8f);
  const long stride = (long)gridDim.x * blockDim.x * 4;
  for (long i = ((long)blockIdx.x * blockDim.x + threadIdx.x) * 4; i < n; i += stride) {
    const float4 v = *reinterpret_cast<const float4*>(x + i);
    ushort4 o;
    o.x = quant_bf16(v.x, s);
    o.y = quant_bf16(v.y, s);
    o.z = quant_bf16(v.z, s);
    o.w = quant_bf16(v.w, s);
    *reinterpret_cast<ushort4*>(q + i) = o;
  }
}

// ===========================================================================
// 256x256 8-phase GEMM (T1+T2+T3+T4+T5), BK=64, 512 thr = 8 waves (2M x 4N).
// out[m][n] = (sum_k Aq[m][k]*Wq[n][k]) * inv_s + bias[n] + resid[m][n]
//
// LDS 128 KB: per operand 2 buffers x 2 K-slices, region = [256 rows][32 k]
// bf16 = 16 KB. Staged by global_load_lds w=16 (linear dest, inverse-swizzled
// global source); reads use cib ^= (row>>1)&3  -> conflict-free ds_read_b128.
//
// Phase = (M-half, K-slice): 4 A ds_reads (+4 B when M-half==0), 1 half-tile
// stage (2 gload_lds), barrier, setprio(1), 16 MFMA, setprio(0),
// [vmcnt(4) at phases 4 & 8], barrier.
// Staging schedule (iter i, tiles t=2i,2i+1; buf parity = tile parity):
//   p1:A b1ks1<-t+1  p2:B b1ks1<-t+1  p3:A b0ks0<-t+2  p4:B b0ks0<-t+2 [vm4]
//   p5:A b0ks1<-t+2  p6:B b0ks1<-t+2  p7:A b1ks0<-t+3  p8:B b1ks0<-t+3 [vm4]
// Every region is written exactly one phase after its last read; every half
// is forced-landed (vmcnt(4)+barrier) >=1 phase before its first read.
// ===========================================================================
#define BM2 256
#define BN2 256
#define BK2 64
#define NT2 (H_DIM / BK2) /* 16, even */

#define AR(BUF, KS) (((BUF)*2 + (KS)) * 8192)
#define BR(BUF, KS) (32768 + ((BUF)*2 + (KS)) * 8192)

#define STAGE_A(BUF, KS, KOFF)                                                 \
  { __builtin_amdgcn_global_load_lds((gmem_void*)(Abase + aoff0 + (KOFF) + (KS)*32), \
        (lds_void*)(lds + AR(BUF, KS) + c0 * 8), 16, 0, 0);                    \
    __builtin_amdgcn_global_load_lds((gmem_void*)(Abase + aoff1 + (KOFF) + (KS)*32), \
        (lds_void*)(lds + AR(BUF, KS) + c1 * 8), 16, 0, 0); }

#define STAGE_B(BUF, KS, KOFF)                                                 \
  { __builtin_amdgcn_global_load_lds((gmem_void*)(Bbase + aoff0 + (KOFF) + (KS)*32), \
        (lds_void*)(lds + BR(BUF, KS) + c0 * 8), 16, 0, 0);                    \
    __builtin_amdgcn_global_load_lds((gmem_void*)(Bbase + aoff1 + (KOFF) + (KS)*32), \
        (lds_void*)(lds + BR(BUF, KS) + c1 * 8), 16, 0, 0); }

#define WAITVM4 asm volatile("s_waitcnt vmcnt(4)" ::: "memory")
#define WAITVM0 asm volatile("s_waitcnt vmcnt(0)" ::: "memory")

#define PHASE(BUF, KS, MH, READB, STAGE_STMT, VM_STMT)                         \
  {                                                                            \
    _Pragma("unroll")                                                          \
    for (int ii = 0; ii < 4; ii++)                                             \
      af[ii] = *reinterpret_cast<const bf16x8*>(lds + AR(BUF, KS) + offA[MH][ii]); \
    if (READB) {                                                               \
      _Pragma("unroll")                                                        \
      for (int jj = 0; jj < 4; jj++)                                           \
        bf[jj] = *reinterpret_cast<const bf16x8*>(lds + BR(BUF, KS) + offB[jj]); \
    }                                                                          \
    STAGE_STMT;                                                                \
    __builtin_amdgcn_s_barrier();                                              \
    __builtin_amdgcn_s_setprio(1);                                             \
    _Pragma("unroll")                                                          \
    for (int ii = 0; ii < 4; ii++)                                             \
      _Pragma("unroll")                                                        \
      for (int jj = 0; jj < 4; jj++)                                           \
        acc[(MH)*4 + ii][jj] = __builtin_amdgcn_mfma_f32_16x16x32_bf16(        \
            af[ii], bf[jj], acc[(MH)*4 + ii][jj], 0, 0, 0);                    \
    __builtin_amdgcn_s_setprio(0);                                             \
    VM_STMT;                                                                   \
    __builtin_amdgcn_s_barrier();                                              \
  }

__global__ __launch_bounds__(512, 2) void gemm_q8p_kernel(
    const unsigned short* __restrict__ Aq,   // [M][1024] bf16 ints
    const unsigned short* __restrict__ Wq,   // [1024][1024] bf16 ints
    const float* __restrict__ bias,
    const float* __restrict__ resid,
    const float* __restrict__ scales,
    float* __restrict__ out, int M) {
  __shared__ __attribute__((aligned(16))) unsigned short lds[65536];  // 128 KB

  const int nbn = H_DIM / BN2;                 // 4
  const int nwg = (M / BM2) * nbn;             // 512
  const int orig = blockIdx.x;
  const int cpx = nwg >> 3;
  const int wg = ((nwg & 7) == 0) ? ((orig & 7) * cpx + (orig >> 3)) : orig;
  const int bn = wg & (nbn - 1), bm = wg / nbn;
  const int m0 = bm * BM2, n0 = bn * BN2;

  const int t = threadIdx.x;
  const int lane = t & 63, wid = t >> 6;
  const int wr = wid >> 2, wc = wid & 3;       // 2x4 wave grid
  const int lrow = lane & 15, lgrp = lane >> 4;

  const float amax_h = fmaxf(scales[0], 1e-8f);
  const float amax_w = fmaxf(scales[1], 1e-8f);
  const float inv_s = (amax_h * amax_w) / (QMAX * QMAX);

  // --- staging constants: linear LDS chunk c -> global (row, cib^swz(row)) ---
  const int c0 = t, c1 = t + 512;
  const int row0 = c0 >> 2, cib0 = c0 & 3;
  const int row1 = c1 >> 2, cib1 = c1 & 3;
  const unsigned aoff0 = (unsigned)row0 * H_DIM + (unsigned)((cib0 ^ ((row0 >> 1) & 3)) * 8);
  const unsigned aoff1 = (unsigned)row1 * H_DIM + (unsigned)((cib1 ^ ((row1 >> 1) & 3)) * 8);
  const unsigned short* Abase = Aq + (size_t)m0 * H_DIM;
  const unsigned short* Bbase = Wq + (size_t)n0 * H_DIM;

  // --- per-thread LDS read offsets (ushorts), swizzled ---
  int offA[2][4], offB[4];
#pragma unroll
  for (int mh = 0; mh < 2; mh++)
#pragma unroll
    for (int ii = 0; ii < 4; ii++) {
      const int r = wr * 128 + mh * 64 + ii * 16 + lrow;
      offA[mh][ii] = r * 32 + ((lgrp ^ ((r >> 1) & 3)) * 8);
    }
#pragma unroll
  for (int jj = 0; jj < 4; jj++) {
    const int r = wc * 64 + jj * 16 + lrow;
    offB[jj] = r * 32 + ((lgrp ^ ((r >> 1) & 3)) * 8);
  }

  f32x4 acc[8][4];
#pragma unroll
  for (int i = 0; i < 8; i++)
#pragma unroll
    for (int j = 0; j < 4; j++)
#pragma unroll
      for (int r = 0; r < 4; r++) acc[i][j][r] = 0.f;

  bf16x8 af[4], bf[4];

  // --- prologue: tile0 (all 4 halves, buf0) + tile1 ks0 (buf1) ---
  STAGE_A(0, 0, 0); STAGE_B(0, 0, 0);
  STAGE_A(0, 1, 0); STAGE_B(0, 1, 0);
  STAGE_A(1, 0, BK2); STAGE_B(1, 0, BK2);
  WAITVM4;  // tile0 fully landed; tile1-ks0 (2 halves) may remain in flight
  __builtin_amdgcn_s_barrier();

  // --- main loop: 2 K-tiles per iteration ---
  for (int i = 0; i < NT2 / 2; ++i) {
    const int kt1 = (2 * i + 1) * BK2;
    const int kt2 = (2 * i + 2) * BK2;
    const int kt3 = (2 * i + 3) * BK2;
    const bool s2 = (2 * i + 2) < NT2;
    const bool s3 = (2 * i + 3) < NT2;
    const bool last = (i == NT2 / 2 - 1);

    PHASE(0, 0, 0, true,  { STAGE_A(1, 1, kt1); }, {})                       // p1
    PHASE(0, 0, 1, false, { STAGE_B(1, 1, kt1); }, {})                       // p2
    PHASE(0, 1, 0, true,  { if (s2) STAGE_A(0, 0, kt2); }, {})               // p3
    PHASE(0, 1, 1, false, { if (s2) STAGE_B(0, 0, kt2); },
          { if (last) { WAITVM0; } else { WAITVM4; } })                      // p4
    PHASE(1, 0, 0, true,  { if (s2) STAGE_A(0, 1, kt2); }, {})               // p5
    PHASE(1, 0, 1, false, { if (s2) STAGE_B(0, 1, kt2); }, {})               // p6
    PHASE(1, 1, 0, true,  { if (s3) STAGE_A(1, 0, kt3); }, {})               // p7
    PHASE(1, 1, 1, false, { if (s3) STAGE_B(1, 0, kt3); },
          { if (!last) { WAITVM4; } })                                       // p8
  }

  // --- epilogue: dequant + bias + residual ---
#pragma unroll
  for (int nf = 0; nf < 4; nf++) {
    const int col = n0 + wc * 64 + nf * 16 + lrow;
    const float bv = bias[col];
#pragma unroll
    for (int mf = 0; mf < 8; mf++) {
      const int rw0 = m0 + wr * 128 + mf * 16 + lgrp * 4;
#pragma unroll
      for (int r = 0; r < 4; r++) {
        const size_t off = (size_t)(rw0 + r) * H_DIM + col;
        out[off] = acc[mf][nf][r] * inv_s + bv + resid[off];
      }
    }
  }
}

// ---------------------------------------------------------------------------
// Fallback (round-2 validated): m97-structure 128x128 GEMM, pre-quantized A.
// ---------------------------------------------------------------------------
#define BM 128
#define BN 128
#define BK 32

__global__ __launch_bounds__(256, 4) void gemm_q_kernel(
    const unsigned short* __restrict__ Aq, const unsigned short* __restrict__ Wq,
    const float* __restrict__ bias, const float* __restrict__ resid,
    const float* __restrict__ scales, float* __restrict__ out, int M) {
  __shared__ __attribute__((aligned(16))) unsigned short As[BM * BK];
  __shared__ __attribute__((aligned(16))) unsigned short Bs[BN * BK];
  const int nwg = (M / BM) * (H_DIM / BN);
  const int cpx = nwg >> 3;
  const int orig = blockIdx.x;
  const int wg = ((nwg & 7) == 0) ? ((orig & 7) * cpx + (orig >> 3)) : orig;
  const int bn = wg & 7, bm = wg >> 3;
  const int m0 = bm * BM, n0 = bn * BN;
  const int t = threadIdx.x;
  const int lane = t & 63, wid = t >> 6;
  const int wr = wid >> 1, wc = wid & 1;
  const int lrow = lane & 15, lgrp = lane >> 4;
  const float amax_h = fmaxf(scales[0], 1e-8f);
  const float amax_w = fmaxf(scales[1], 1e-8f);
  const float inv_s = (amax_h * amax_w) / (QMAX * QMAX);
  const int c0 = t, c1 = t + 256;
  const int ar0 = c0 >> 2, ac0 = (c0 & 3) * 8;
  const int ar1 = c1 >> 2, ac1 = (c1 & 3) * 8;
  const unsigned short* Ab = Aq + (size_t)m0 * H_DIM;
  const unsigned short* Bb = Wq + (size_t)n0 * H_DIM;
  f32x4 acc[4][4];
#pragma unroll
  for (int i = 0; i < 4; i++)
#pragma unroll
    for (int j = 0; j < 4; j++)
#pragma unroll
      for (int r = 0; r < 4; r++) acc[i][j][r] = 0.f;
  for (int k0 = 0; k0 < H_DIM; k0 += BK) {
    __builtin_amdgcn_global_load_lds((gmem_void*)(Ab + (size_t)ar0 * H_DIM + k0 + ac0),
                                     (lds_void*)(As + c0 * 8), 16, 0, 0);
    __builtin_amdgcn_global_load_lds((gmem_void*)(Ab + (size_t)ar1 * H_DIM + k0 + ac1),
                                     (lds_void*)(As + c1 * 8), 16, 0, 0);
    __builtin_amdgcn_global_load_lds((gmem_void*)(Bb + (size_t)ar0 * H_DIM + k0 + ac0),
                                     (lds_void*)(Bs + c0 * 8), 16, 0, 0);
    __builtin_amdgcn_global_load_lds((gmem_void*)(Bb + (size_t)ar1 * H_DIM + k0 + ac1),
                                     (lds_void*)(Bs + c1 * 8), 16, 0, 0);
    __syncthreads();
    bf16x8 af[4], bfr[4];
#pragma unroll
    for (int i = 0; i < 4; i++)
      af[i] = *reinterpret_cast<const bf16x8*>(As + (wr * 64 + i * 16 + lrow) * BK + lgrp * 8);
#pragma unroll
    for (int j = 0; j < 4; j++)
      bfr[j] = *reinterpret_cast<const bf16x8*>(Bs + (wc * 64 + j * 16 + lrow) * BK + lgrp * 8);
#pragma unroll
    for (int i = 0; i < 4; i++)
#pragma unroll
      for (int j = 0; j < 4; j++)
        acc[i][j] = __builtin_amdgcn_mfma_f32_16x16x32_bf16(af[i], bfr[j], acc[i][j], 0, 0, 0);
    __syncthreads();
  }
#pragma unroll
  for (int j = 0; j < 4; j++) {
    const int col = n0 + wc * 64 + j * 16 + lrow;
    const float bv = bias[col];
#pragma unroll
    for (int i = 0; i < 4; i++) {
      const int row0 = m0 + wr * 64 + i * 16 + lgrp * 4;
#pragma unroll
      for (int r = 0; r < 4; r++) {
        const size_t off = (size_t)(row0 + r) * H_DIM + col;
        out[off] = acc[i][j][r] * inv_s + bv + resid[off];
      }
    }
  }
}

// ---------------------------------------------------------------------------
// Fallback fused GEMM (round-1 validated): A quantized on the fly from fp32.
// ---------------------------------------------------------------------------
__global__ __launch_bounds__(256, 2) void gemm_fused_kernel(
    const float* __restrict__ A, const unsigned short* __restrict__ Wq,
    const float* __restrict__ bias, const float* __restrict__ resid,
    const float* __restrict__ scales, float* __restrict__ out, int M) {
  __shared__ unsigned short As[BM][40];
  __shared__ unsigned short Bs[BN][40];
  const int nbm = M / BM;
  const int bm = blockIdx.x % nbm, bn = blockIdx.x / nbm;
  const int m0 = bm * BM, n0 = bn * BN;
  const int t = threadIdx.x;
  const int lane = t & 63, wid = t >> 6;
  const int wr = wid >> 1, wc = wid & 1;
  const int lrow = lane & 15, lgrp = lane >> 4;
  const float amax_h = fmaxf(scales[0], 1e-8f);
  const float amax_w = fmaxf(scales[1], 1e-8f);
  const float sh = QMAX / amax_h;
  const float inv_s = (amax_h * amax_w) / (QMAX * QMAX);
  f32x4 acc[4][4];
#pragma unroll
  for (int i = 0; i < 4; i++)
#pragma unroll
    for (int j = 0; j < 4; j++)
#pragma unroll
      for (int r = 0; r < 4; r++) acc[i][j][r] = 0.f;
  for (int k0 = 0; k0 < H_DIM; k0 += BK) {
#pragma unroll
    for (int j = 0; j < 4; ++j) {
      const int f = j * 256 + t;
      const int r = f >> 3, c4 = f & 7;
      const float4 v = *reinterpret_cast<const float4*>(A + (size_t)(m0 + r) * H_DIM + k0 + c4 * 4);
      ushort4 q;
      q.x = quant_bf16(v.x, sh); q.y = quant_bf16(v.y, sh);
      q.z = quant_bf16(v.z, sh); q.w = quant_bf16(v.w, sh);
      *reinterpret_cast<ushort4*>(&As[r][c4 * 4]) = q;
    }
#pragma unroll
    for (int j = 0; j < 2; ++j) {
      const int f = j * 256 + t;
      const int r = f >> 2, cb = f & 3;
      const uint4 v = *reinterpret_cast<const uint4*>(Wq + (size_t)(n0 + r) * H_DIM + k0 + cb * 8);
      *reinterpret_cast<uint4*>(&Bs[r][cb * 8]) = v;
    }
    __syncthreads();
    bf16x8 af[4], bfr[4];
#pragma unroll
    for (int i = 0; i < 4; i++)
      af[i] = *reinterpret_cast<const bf16x8*>(&As[wr * 64 + i * 16 + lrow][lgrp * 8]);
#pragma unroll
    for (int j = 0; j < 4; j++)
      bfr[j] = *reinterpret_cast<const bf16x8*>(&Bs[wc * 64 + j * 16 + lrow][lgrp * 8]);
#pragma unroll
    for (int i = 0; i < 4; i++)
#pragma unroll
      for (int j = 0; j < 4; j++)
        acc[i][j] = __builtin_amdgcn_mfma_f32_16x16x32_bf16(af[i], bfr[j], acc[i][j], 0, 0, 0);
    __syncthreads();
  }
#pragma unroll
  for (int j = 0; j < 4; j++) {
    const int col = n0 + wc * 64 + j * 16 + lrow;
    const float bv = bias[col];
#pragma unroll
    for (int i = 0; i < 4; i++) {
      const int row0 = m0 + wr * 64 + i * 16 + lgrp * 4;
#pragma unroll
      for (int r = 0; r < 4; r++) {
        const size_t off = (size_t)(row0 + r) * H_DIM + col;
        out[off] = acc[i][j][r] * inv_s + bv + resid[off];
      }
    }
  }
}

// ---------------------------------------------------------------------------
// In-place LayerNorm over last dim (1024). One block (256 thr) per row.
// ---------------------------------------------------------------------------
__global__ __launch_bounds__(256) void ln_kernel(
    float* __restrict__ y, const float* __restrict__ gamma,
    const float* __restrict__ beta) {
  const size_t base = (size_t)blockIdx.x * H_DIM + threadIdx.x * 4;
  const float4 v = *reinterpret_cast<const float4*>(y + base);
  float s = v.x + v.y + v.z + v.w;
  float ss = v.x * v.x + v.y * v.y + v.z * v.z + v.w * v.w;
#pragma unroll
  for (int off = 32; off > 0; off >>= 1) {
    s += __shfl_down(s, off);
    ss += __shfl_down(ss, off);
  }
  __shared__ float red[8];
  const int lane = threadIdx.x & 63, w = threadIdx.x >> 6;
  if (lane == 0) { red[w] = s; red[4 + w] = ss; }
  __syncthreads();
  const float stot = red[0] + red[1] + red[2] + red[3];
  const float sstot = red[4] + red[5] + red[6] + red[7];
  const float mu = stot * (1.0f / H_DIM);
  const float var = fmaxf(sstot * (1.0f / H_DIM) - mu * mu, 0.f);
  const float rs = rsqrtf(var + 1e-12f);
  const float4 g = *reinterpret_cast<const float4*>(gamma + threadIdx.x * 4);
  const float4 b = *reinterpret_cast<const float4*>(beta + threadIdx.x * 4);
  float4 o;
  o.x = (v.x - mu) * rs * g.x + b.x;
  o.y = (v.y - mu) * rs * g.y + b.y;
  o.z = (v.z - mu) * rs * g.z + b.z;
  o.w = (v.w - mu) * rs * g.w + b.w;
  *reinterpret_cast<float4*>(y + base) = o;
}

extern "C" void kernel_launch(void* const* d_in, const int* in_sizes, int n_in,
                              void* d_out, int out_size, void* d_ws, size_t ws_size,
                              hipStream_t stream) {
  const float* hidden = (const float*)d_in[0];
  const float* resid  = (const float*)d_in[1];
  const float* weight = (const float*)d_in[2];
  const float* bias   = (const float*)d_in[3];
  const float* gamma  = (const float*)d_in[4];
  const float* beta   = (const float*)d_in[5];
  float* out = (float*)d_out;

  const long nh = (long)in_sizes[0];   // B*S*H
  const int M = (int)(nh / H_DIM);     // 32768

  float* scales = (float*)d_ws;                               // [0]=amax_h,[1]=amax_w
  unsigned short* Wq = (unsigned short*)((char*)d_ws + 256);  // 2 MB
  unsigned short* Aq = Wq + (size_t)H_DIM * H_DIM;            // 64 MB
  const size_t need = 256 + (size_t)H_DIM * H_DIM * 2 + (size_t)nh * 2;

  hipMemsetAsync(d_ws, 0, 8, stream);
  absmax_clip_kernel<<<2048, 256, 0, stream>>>(hidden, nh, scales + 0);
  absmax_clip_kernel<<<256, 256, 0, stream>>>(weight, (long)H_DIM * H_DIM, scales + 1);
  quant_kernel<<<1024, 256, 0, stream>>>(weight, Wq, scales + 1, (long)H_DIM * H_DIM);

  if (ws_size >= need && (M % BM) == 0) {
    quant_kernel<<<2048, 256, 0, stream>>>(hidden, Aq, scales + 0, nh);
    if ((M % BM2) == 0) {
      gemm_q8p_kernel<<<(M / BM2) * (H_DIM / BN2), 512, 0, stream>>>(
          Aq, Wq, bias, resid, scales, out, M);
    } else {
      gemm_q_kernel<<<(M / BM) * (H_DIM / BN), 256, 0, stream>>>(
          Aq, Wq, bias, resid, scales, out, M);
    }
  } else {
    gemm_fused_kernel<<<(M / BM) * (H_DIM / BN), 256, 0, stream>>>(
        hidden, Wq, bias, resid, scales, out, M);
  }
  ln_kernel<<<M, 256, 0, stream>>>(out, gamma, beta);
}